// Round 5
// baseline (126.384 us; speedup 1.0000x reference)
//
#include <hip/hip_runtime.h>

// Receptive-field spike encoder:
//   out[t, b, d] = ( clip( (int)(scaling[d] * |x[b] - center[d]|), 0, T-1 ) == t ) ? 1 : 0
// Output [T, B, N=16] float32, 512 MiB -> write-BW-bound.
//
// Round-5 = round-4 with the compile fix: __builtin_nontemporal_store needs a
// NATIVE vector type (ext_vector_type), not HIP's float4 class.
// Theory: output is streaming (written once, never re-read) and 2x the 256 MiB
// L3 — regular stores pay write-allocate + dirty-evict churn in TCC; `nt`
// stores bypass that. Round-3 coalescing kept: lane i stores 16B at
// base + i*16 -> each wave store instruction covers a contiguous 1 KiB.

typedef float f32x4 __attribute__((ext_vector_type(4)));

#define TBLK 16  // t-planes per thread

__global__ void rf_encode_q(const float* __restrict__ x,
                            const float* __restrict__ center,
                            const float* __restrict__ scaling,
                            float* __restrict__ out,
                            int B, int T) {
    int q = blockIdx.x * blockDim.x + threadIdx.x;   // [0, B*4)
    if (q >= B * 4) return;
    int b  = q >> 2;
    int d0 = (q & 3) * 4;

    float xb = x[b];

    // spike times for this thread's 4 receptive fields (t-independent)
    int ts[4];
    #pragma unroll
    for (int k = 0; k < 4; ++k) {
        // exact numpy op sequence: sub, abs, mul, trunc-to-int32, clip
        float dist = fabsf(xb - center[d0 + k]);
        int v = (int)(scaling[d0 + k] * dist);
        ts[k] = min(max(v, 0), T - 1);
    }

    int t0 = blockIdx.y * TBLK;
    // flat float offset of (t0, b, d0); advances by B*16 floats per t-plane
    float* o = out + ((long long)t0 * B + (long long)b) * 16 + d0;
    const long long tstride = (long long)B * 16;

    #pragma unroll
    for (int i = 0; i < TBLK; ++i) {
        int t = t0 + i;
        if (t >= T) break;
        f32x4 r;
        r.x = (ts[0] == t) ? 1.0f : 0.0f;
        r.y = (ts[1] == t) ? 1.0f : 0.0f;
        r.z = (ts[2] == t) ? 1.0f : 0.0f;
        r.w = (ts[3] == t) ? 1.0f : 0.0f;
        __builtin_nontemporal_store(r, reinterpret_cast<f32x4*>(o));
        o += tstride;
    }
}

// generic fallback for N not handled by the fast path (not expected here)
__global__ void rf_encode_generic(const float* __restrict__ x,
                                  const float* __restrict__ center,
                                  const float* __restrict__ scaling,
                                  float* __restrict__ out,
                                  int B, int N, int T) {
    long long tid = (long long)blockIdx.x * blockDim.x + threadIdx.x;
    long long total = (long long)T * B;
    if (tid >= total) return;
    int b = (int)(tid % B);
    int t = (int)(tid / B);
    float xb = x[b];
    float* o = out + ((long long)t * B + (long long)b) * N;
    for (int d = 0; d < N; ++d) {
        float dist = fabsf(xb - center[d]);
        int v = (int)(scaling[d] * dist);
        v = min(max(v, 0), T - 1);
        o[d] = (v == t) ? 1.0f : 0.0f;
    }
}

extern "C" void kernel_launch(void* const* d_in, const int* in_sizes, int n_in,
                              void* d_out, int out_size, void* d_ws, size_t ws_size,
                              hipStream_t stream) {
    const float* x       = (const float*)d_in[0];
    const float* center  = (const float*)d_in[1];
    const float* scaling = (const float*)d_in[2];
    float* out = (float*)d_out;

    int B = in_sizes[0];
    int N = in_sizes[1];
    int T = (int)((long long)out_size / ((long long)B * (long long)N));

    if (N == 16) {
        const int block = 256;
        dim3 grid((B * 4 + block - 1) / block, (T + TBLK - 1) / TBLK);
        rf_encode_q<<<grid, block, 0, stream>>>(x, center, scaling, out, B, T);
    } else {
        long long total = (long long)T * B;
        const int block = 256;
        int blocks = (int)((total + block - 1) / block);
        rf_encode_generic<<<blocks, block, 0, stream>>>(x, center, scaling, out, B, N, T);
    }
}

// Round 6
// 107.392 us; speedup vs baseline: 1.1768x; 1.1768x over previous
//
#include <hip/hip_runtime.h>

// Receptive-field spike encoder:
//   out[t, b, d] = ( clip( (int)(scaling[d] * |x[b] - center[d]|), 0, T-1 ) == t ) ? 1 : 0
// Output [T, B, N=16] float32, 512 MiB -> write-BW-bound.
//
// Round-6: contiguous write stream. Rounds 3/5 had each block write 16 x 4KiB
// chunks strided 8 MiB apart (one per t-plane) -> thousands of disjoint write
// streams in flight, thrashing TCC write-combine / DRAM row buffers, capping
// at 4.26 TB/s while fillBuffer's linear stream hits 6.7 TB/s. Now each block
// owns ONE contiguous 64 KiB chunk of the flat [T,B,16] output (128 blocks
// per plane), so the chip-wide store stream marches linearly.
// Per-instruction coalescing kept: lane i stores 16B at base + i*16.

typedef float f32x4 __attribute__((ext_vector_type(4)));

#define ITERS 16  // 16B chunks per thread; block = 256 thr * 16 * 16B = 64 KiB

__global__ void rf_encode_lin(const float* __restrict__ x,
                              const float* __restrict__ center,
                              const float* __restrict__ scaling,
                              float* __restrict__ out,
                              int logB, int Bmask, int T, long long total_chunks) {
    // chunk index c = one 16B quarter-row; row rb = c>>2 -> (t = rb>>logB, b = rb&Bmask)
    long long c0 = (long long)blockIdx.x * (blockDim.x * ITERS) + threadIdx.x;

    // quarter (which 4 of the 16 receptive fields) is loop-invariant:
    // block base and per-iter stride are multiples of 4.
    int qt = threadIdx.x & 3;
    f32x4 c4 = reinterpret_cast<const f32x4*>(center)[qt];
    f32x4 s4 = reinterpret_cast<const f32x4*>(scaling)[qt];

    long long rb0 = c0 >> 2;

    #pragma unroll
    for (int it = 0; it < ITERS; ++it) {
        long long c = c0 + (long long)it * blockDim.x;
        if (c >= total_chunks) break;
        long long rb = rb0 + (long long)it * (blockDim.x >> 2);
        int b = (int)(rb & Bmask);
        int t = (int)(rb >> logB);

        float xb = x[b];
        f32x4 r;
        {   // exact numpy op sequence: sub, abs, mul, trunc-to-int32, clip
            int v0 = (int)(s4.x * fabsf(xb - c4.x)); v0 = min(max(v0, 0), T - 1);
            int v1 = (int)(s4.y * fabsf(xb - c4.y)); v1 = min(max(v1, 0), T - 1);
            int v2 = (int)(s4.z * fabsf(xb - c4.z)); v2 = min(max(v2, 0), T - 1);
            int v3 = (int)(s4.w * fabsf(xb - c4.w)); v3 = min(max(v3, 0), T - 1);
            r.x = (v0 == t) ? 1.0f : 0.0f;
            r.y = (v1 == t) ? 1.0f : 0.0f;
            r.z = (v2 == t) ? 1.0f : 0.0f;
            r.w = (v3 == t) ? 1.0f : 0.0f;
        }
        __builtin_nontemporal_store(r, reinterpret_cast<f32x4*>(out) + c);
    }
}

// generic fallback (N != 16 or B not a power of two)
__global__ void rf_encode_generic(const float* __restrict__ x,
                                  const float* __restrict__ center,
                                  const float* __restrict__ scaling,
                                  float* __restrict__ out,
                                  int B, int N, int T) {
    long long tid = (long long)blockIdx.x * blockDim.x + threadIdx.x;
    long long total = (long long)T * B;
    if (tid >= total) return;
    int b = (int)(tid % B);
    int t = (int)(tid / B);
    float xb = x[b];
    float* o = out + ((long long)t * B + (long long)b) * N;
    for (int d = 0; d < N; ++d) {
        float dist = fabsf(xb - center[d]);
        int v = (int)(scaling[d] * dist);
        v = min(max(v, 0), T - 1);
        o[d] = (v == t) ? 1.0f : 0.0f;
    }
}

extern "C" void kernel_launch(void* const* d_in, const int* in_sizes, int n_in,
                              void* d_out, int out_size, void* d_ws, size_t ws_size,
                              hipStream_t stream) {
    const float* x       = (const float*)d_in[0];
    const float* center  = (const float*)d_in[1];
    const float* scaling = (const float*)d_in[2];
    float* out = (float*)d_out;

    int B = in_sizes[0];
    int N = in_sizes[1];
    int T = (int)((long long)out_size / ((long long)B * (long long)N));

    bool bpow2 = (B & (B - 1)) == 0;
    if (N == 16 && bpow2) {
        int logB = 0;
        while ((1 << logB) < B) ++logB;
        long long total_chunks = (long long)out_size / 4;  // 16B chunks
        const int block = 256;
        long long chunks_per_block = (long long)block * ITERS;
        int nblocks = (int)((total_chunks + chunks_per_block - 1) / chunks_per_block);
        rf_encode_lin<<<nblocks, block, 0, stream>>>(x, center, scaling, out,
                                                     logB, B - 1, T, total_chunks);
    } else {
        long long total = (long long)T * B;
        const int block = 256;
        int blocks = (int)((total + block - 1) / block);
        rf_encode_generic<<<blocks, block, 0, stream>>>(x, center, scaling, out, B, N, T);
    }
}